// Round 10
// baseline (1223.513 us; speedup 1.0000x reference)
//
#include <hip/hip_runtime.h>
#include <hip/hip_bf16.h>

#define EMB   256
#define KSORT 30
#define BATCH 48
#define NGPI  11
#define GG    528
#define NPG   192
#define EPG   384
#define DCH   769
#define GC    528                // graphs (single chunk)
#define MC    (GC*NPG)           // 101376 nodes
#define EC    (GC*EPG)           // 202752 edges
#define FQ    44                 // dense1 feature splits
#define FCH   (2816/FQ)          // 64 features per split
#define KB5   5                  // conv5 k-rows per block

__device__ __forceinline__ int clampi(int v, int lo, int hi) {
  return v < lo ? lo : (v > hi ? hi : v);
}

// ------------- static device scratch (~270 MB BSS; NEVER as host-side args) -
__device__ __attribute__((aligned(16))) float g_c1[MC * EMB];
__device__ __attribute__((aligned(16))) float g_c2[MC * EMB];
__device__ __attribute__((aligned(16))) float g_c3[MC * EMB];
__device__ __attribute__((aligned(16))) float g_dis[MC];
__device__ __attribute__((aligned(16))) float g_s4[MC];      // layer-4 GEMV out
__device__ __attribute__((aligned(16))) float g_x4[MC];
__device__ __attribute__((aligned(16))) int   g_indptr[MC + 1];
__device__ __attribute__((aligned(16))) int   g_ssrc[EC];
__device__ __attribute__((aligned(16))) int   g_idx[GC * KSORT];
__device__ __attribute__((aligned(16))) float g_w5t[DCH * 128];
__device__ __attribute__((aligned(16))) float g_w6t[640 * 256];
__device__ __attribute__((aligned(16))) float g_y[GC * 128 * 30];
__device__ __attribute__((aligned(16))) float g_z[GG * 2816];
__device__ __attribute__((aligned(16))) float g_hp[NGPI * FQ * BATCH * 256];
__device__ __attribute__((aligned(16))) float g_h[BATCH * 256];

__device__ __forceinline__ float* selbuf(int s) {
  return s == 0 ? g_c1 : (s == 1 ? g_c2 : g_c3);
}

// -------- graph-local CSR build + degree norm (all 528 graphs) --------------
__global__ __launch_bounds__(192) void build_csr_k(const int* __restrict__ src,
    const int* __restrict__ dst, int g0) {
  __shared__ int cnt[NPG];
  __shared__ int offs[NPG];
  int g = blockIdx.x, t = threadIdx.x;
  int gg = g0 + g;
  cnt[t] = 0;
  __syncthreads();
  int ebase = gg * EPG, gnb = gg * NPG, lnb = g * NPG;
  for (int e = t; e < EPG; e += 192) {
    int dl = clampi(dst[ebase + e] - gnb, 0, NPG - 1);
    atomicAdd(&cnt[dl], 1);
  }
  __syncthreads();
  if (t == 0) {
    int run = g * EPG;
    for (int i = 0; i < NPG; i++) { offs[i] = run; run += cnt[i]; }
  }
  __syncthreads();
  g_indptr[lnb + t] = offs[t];
  g_dis[lnb + t] = 1.0f / sqrtf(1.0f + (float)cnt[t]);
  if (g == 0 && t == 0) g_indptr[MC] = EC;
  __syncthreads();
  for (int e = t; e < EPG; e += 192) {
    int ee = ebase + e;
    int dl = clampi(dst[ee] - gnb, 0, NPG - 1);
    int pos = clampi(atomicAdd(&offs[dl], 1), 0, EC - 1);
    g_ssrc[pos] = clampi(src[ee] - gnb, 0, NPG - 1) + lnb;
  }
}

// ---- FUSED GCN layer: per-graph GEMM + in-LDS aggregation + bias + tanh ----
// Tile = 192 rows (one graph) x 64 cols; 192 threads; 8x8 micro-tile (same
// DS:FMA ratio as the proven R6 gemm: 2 A-b128 broadcast + 1 Bs-b128 + 1
// L1-dwordx4 per 64 FMA). H parked in LDS after the k-loop (aliases As/Bs);
// aggregation runs in-block -> the g_tb HBM round-trip (~300MB/layer) is
// deleted. XCD-grouped block map (bijective, 2112 = 8 XCD x 66 graphs x 4
// col-blocks): each graph's 4 col-blocks land on ONE XCD -> A fetched once
// (fixes R7's 234MB FETCH). LDS 52.2KB caps 3 blocks/CU -> VGPR slack to
// ~220, no spill risk. Math order (k ascending, self-then-CSR-edge agg,
// bias, tanh) identical to gemm_k+agg_k -> bit-stable output.
template<bool AX>
__global__ __launch_bounds__(192) void gcn_k(const float* __restrict__ Ax,
    int asel, int osel, const float* __restrict__ W,
    const float* __restrict__ bias, int Kd) {
  __shared__ float lds[13056];           // As 3072 | Bs 576 ; H 13056 aliased
  const int bx = blockIdx.x;
  const int g = (bx & 7) * 66 + (bx >> 5);
  const int cb = (bx >> 3) & 3;
  const int t = threadIdx.x;
  const int tx = t & 7, ty = t >> 3;
  const int n0 = cb * 64;
  const int base = g * NPG;
  float acc[8][8];
#pragma unroll
  for (int i = 0; i < 8; i++)
#pragma unroll
    for (int j = 0; j < 8; j++) acc[i][j] = 0.f;
  const float* Ap = (AX ? Ax : selbuf(asel)) + (size_t)base * Kd;
  const float* arp = Ap + (size_t)t * Kd;         // thread stages row t
  const int brow = t >> 3;                        // Bs stage row (t<128)
  const float* bsp = W + (size_t)brow * EMB + n0 + tx * 8;
  float* Bs = lds + 3072;
  const int nt = Kd >> 4;
  float4 pa0 = *(const float4*)(arp);
  float4 pa1 = *(const float4*)(arp + 4);
  float4 pa2 = *(const float4*)(arp + 8);
  float4 pa3 = *(const float4*)(arp + 12);
  float4 pb;
  if (t < 128) pb = *(const float4*)(bsp);
  for (int it = 0; it < nt; ++it) {
    lds[ 0 * 192 + t] = pa0.x; lds[ 1 * 192 + t] = pa0.y;
    lds[ 2 * 192 + t] = pa0.z; lds[ 3 * 192 + t] = pa0.w;
    lds[ 4 * 192 + t] = pa1.x; lds[ 5 * 192 + t] = pa1.y;
    lds[ 6 * 192 + t] = pa1.z; lds[ 7 * 192 + t] = pa1.w;
    lds[ 8 * 192 + t] = pa2.x; lds[ 9 * 192 + t] = pa2.y;
    lds[10 * 192 + t] = pa2.z; lds[11 * 192 + t] = pa2.w;
    lds[12 * 192 + t] = pa3.x; lds[13 * 192 + t] = pa3.y;
    lds[14 * 192 + t] = pa3.z; lds[15 * 192 + t] = pa3.w;
    if (t < 128) *(float4*)&Bs[brow * 36 + tx * 4] = pb;
    __syncthreads();
    if (it + 1 < nt) {                  // prefetch next k-slice into regs
      const float* ap = arp + (it + 1) * 16;
      pa0 = *(const float4*)(ap);
      pa1 = *(const float4*)(ap + 4);
      pa2 = *(const float4*)(ap + 8);
      pa3 = *(const float4*)(ap + 12);
      if (t < 128) pb = *(const float4*)(bsp + (size_t)(it + 1) * 16 * EMB);
    }
    const float* Wk = W + (size_t)(it * 16) * EMB + n0 + tx * 8 + 4;
#pragma unroll
    for (int kk = 0; kk < 16; kk++) {
      float a[8], b[8];
      *(float4*)&a[0] = *(const float4*)&lds[kk * 192 + ty * 8];
      *(float4*)&a[4] = *(const float4*)&lds[kk * 192 + ty * 8 + 4];
      *(float4*)&b[0] = *(const float4*)&Bs[kk * 36 + tx * 4];
      *(float4*)&b[4] = *(const float4*)(Wk + (size_t)kk * EMB);
#pragma unroll
      for (int i = 0; i < 8; i++)
#pragma unroll
        for (int j = 0; j < 8; j++) acc[i][j] += a[i] * b[j];
    }
    __syncthreads();
  }
  // ---- park H[192][68] in LDS (As/Bs dead past the trailing barrier) ----
#pragma unroll
  for (int i = 0; i < 8; i++) {
    float* hp = &lds[(ty * 8 + i) * 68 + tx * 8];
    *(float4*)hp = make_float4(acc[i][0], acc[i][1], acc[i][2], acc[i][3]);
    *(float4*)(hp + 4) = make_float4(acc[i][4], acc[i][5], acc[i][6], acc[i][7]);
  }
  __syncthreads();
  // ---- aggregation + bias + tanh for row t (self then CSR edges) ----
  const int n = base + t;
  const float dn = g_dis[n];
  const float sc = dn * dn;
  float4 agv[16];
#pragma unroll
  for (int q = 0; q < 16; q++) {
    float4 v = *(const float4*)&lds[t * 68 + q * 4];
    agv[q] = make_float4(v.x * sc, v.y * sc, v.z * sc, v.w * sc);
  }
  const int beg = g_indptr[n], end = g_indptr[n + 1];
  for (int e = beg; e < end; e++) {
    int s = clampi(g_ssrc[e] - base, 0, NPG - 1);
    float c = g_dis[base + s] * dn;
#pragma unroll
    for (int q = 0; q < 16; q++) {
      float4 v = *(const float4*)&lds[s * 68 + q * 4];
      agv[q].x += v.x * c; agv[q].y += v.y * c;
      agv[q].z += v.z * c; agv[q].w += v.w * c;
    }
  }
  float* outp = selbuf(osel) + (size_t)n * EMB + n0;
  const float4* bv4 = (const float4*)bias + cb * 16;
#pragma unroll
  for (int q = 0; q < 16; q++) {
    float4 bv = bv4[q];
    float4 o;
    o.x = tanhf(agv[q].x + bv.x);
    o.y = tanhf(agv[q].y + bv.y);
    o.z = tanhf(agv[q].z + bv.z);
    o.w = tanhf(agv[q].w + bv.w);
    *(float4*)(outp + q * 4) = o;
  }
}

// ---------------- layer-4 (EMB -> 1) GEMV: g_s4 = c3 . W4 -------------------
__global__ __launch_bounds__(256) void gemm4_k(const float* __restrict__ W4) {
  int n = blockIdx.x * 4 + (threadIdx.x >> 6);
  int lane = threadIdx.x & 63;
  float4 a = *(const float4*)(g_c3 + (size_t)n * EMB + lane * 4);
  float4 w = *(const float4*)(W4 + lane * 4);
  float s = a.x * w.x + a.y * w.y + a.z * w.z + a.w * w.w;
  for (int off = 32; off > 0; off >>= 1) s += __shfl_down(s, off, 64);
  if (lane == 0) g_s4[n] = s;
}

// ---- tail1: per-graph agg4 + bitonic sortpool (exact ports, merged) --------
__global__ __launch_bounds__(256) void tail1_k(const float* __restrict__ b4) {
  __shared__ float x4v[NPG];
  __shared__ float sv[256];
  __shared__ int si[256];
  const int g = blockIdx.x, t = threadIdx.x;
  const int gbase = g * NPG;
  if (t < NPG) {
    int n = gbase + t;
    float dn = g_dis[n];
    float acc = g_s4[n] * dn * dn;
    int beg = g_indptr[n], end = g_indptr[n + 1];
    for (int j = beg; j < end; j++) {
      int s = g_ssrc[j];
      acc += g_s4[s] * g_dis[s] * dn;
    }
    float v = tanhf(acc + b4[0]);
    x4v[t] = v;
    g_x4[n] = v;                       // conv5 reads this
  }
  __syncthreads();
  if (t < NPG) { sv[t] = x4v[t]; si[t] = t; }
  else { sv[t] = -1e30f; si[t] = 1 << 20; }
  __syncthreads();
  for (int k = 2; k <= 256; k <<= 1) {
    for (int j = k >> 1; j > 0; j >>= 1) {
      int ixj = t ^ j;
      if (ixj > t) {
        float v1 = sv[t], v2 = sv[ixj];
        int i1 = si[t], i2 = si[ixj];
        bool before_t = (v1 > v2) || (v1 == v2 && i1 < i2);
        bool up = ((t & k) == 0);
        if (up ? !before_t : before_t) {
          sv[t] = v2; sv[ixj] = v1;
          si[t] = i2; si[ixj] = i1;
        }
      }
      __syncthreads();
    }
  }
  if (t < KSORT) g_idx[g * KSORT + t] = clampi(gbase + si[t], 0, MC - 1);
}

// ---------------- weight transposes -----------------------------------------
__global__ __launch_bounds__(256) void tw5_k(const float* __restrict__ w5) {
  int i = blockIdx.x * 256 + threadIdx.x;  // 128*769
  if (i >= 128 * DCH) return;
  int o = i / DCH, d = i % DCH;
  g_w5t[d * 128 + o] = w5[i];
}
__global__ __launch_bounds__(256) void tw6_k(const float* __restrict__ w6) {
  int i = blockIdx.x * 256 + threadIdx.x;  // 256*640
  if (i >= 256 * 640) return;
  int o = i / 640, ir = i % 640;
  g_w6t[ir * 256 + o] = w6[i];
}

// ------ conv5: gather-GEMM over top-K rows; 5 rows/block, grid (GC,6) -------
__global__ __launch_bounds__(128) void conv5_k(const float* __restrict__ bc5) {
  __shared__ float ar[KB5][772];
  int g = blockIdx.x, kb = blockIdx.y * KB5;
  int t = threadIdx.x;
  for (int kk = 0; kk < KB5; kk++) {
    int n = clampi(g_idx[g * KSORT + kb + kk], 0, MC - 1);
    const float* p1 = g_c1 + (size_t)n * EMB;
    const float* p2 = g_c2 + (size_t)n * EMB;
    const float* p3 = g_c3 + (size_t)n * EMB;
    for (int d = t; d < EMB; d += 128) {
      ar[kk][d] = p1[d];
      ar[kk][EMB + d] = p2[d];
      ar[kk][2 * EMB + d] = p3[d];
    }
    if (t == 0) ar[kk][768] = g_x4[n];
  }
  __syncthreads();
  float acc[KB5];
  float bias = bc5[t];
#pragma unroll
  for (int kk = 0; kk < KB5; kk++) acc[kk] = bias;
  const float* wbase = g_w5t + t;
  int d = 0;
  for (; d + 8 <= DCH; d += 8) {
    float w0 = wbase[(d + 0) * 128], w1 = wbase[(d + 1) * 128];
    float w2 = wbase[(d + 2) * 128], w3 = wbase[(d + 3) * 128];
    float w4 = wbase[(d + 4) * 128], w5 = wbase[(d + 5) * 128];
    float w6 = wbase[(d + 6) * 128], w7 = wbase[(d + 7) * 128];
#pragma unroll
    for (int kk = 0; kk < KB5; kk++) {
      float4 a0 = *(const float4*)&ar[kk][d];
      float4 a1 = *(const float4*)&ar[kk][d + 4];
      acc[kk] += a0.x * w0 + a0.y * w1 + a0.z * w2 + a0.w * w3 +
                 a1.x * w4 + a1.y * w5 + a1.z * w6 + a1.w * w7;
    }
  }
  for (; d < DCH; d++) {
    float wv = wbase[d * 128];
#pragma unroll
    for (int kk = 0; kk < KB5; kk++) acc[kk] += ar[kk][d] * wv;
  }
#pragma unroll
  for (int kk = 0; kk < KB5; kk++)
    g_y[(size_t)g * 3840 + t * KSORT + kb + kk] = fmaxf(acc[kk], 0.f);
}

// ------ conv6 (128ch, k=5) per graph; maxpool(2,2) fused into staging -------
__global__ __launch_bounds__(256) void conv6_k(const float* __restrict__ bc6,
                                               int g0) {
  __shared__ float s[128 * 16];
  int g = blockIdx.x, t = threadIdx.x;
  for (int i = t; i < 1920; i += 256) {
    int ch = i / 15, j = i % 15;
    const float* yp = g_y + (size_t)g * 3840 + ch * 30 + 2 * j;
    s[ch * 16 + j] = fmaxf(yp[0], yp[1]);
  }
  __syncthreads();
  float acc[11];
  float bias = bc6[t];
#pragma unroll
  for (int q = 0; q < 11; q++) acc[q] = bias;
  for (int i = 0; i < 128; i += 2) {
    float wA[5], wB[5];
#pragma unroll
    for (int r = 0; r < 5; r++) {
      wA[r] = g_w6t[(i * 5 + r) * 256 + t];
      wB[r] = g_w6t[((i + 1) * 5 + r) * 256 + t];
    }
    const float* sA = &s[i * 16];
    const float* sB = &s[(i + 1) * 16];
#pragma unroll
    for (int r = 0; r < 5; r++)
#pragma unroll
      for (int q = 0; q < 11; q++)
        acc[q] += sA[r + q] * wA[r] + sB[r + q] * wB[r];
  }
#pragma unroll
  for (int q = 0; q < 11; q++)
    g_z[(size_t)(g0 + g) * 2816 + t * 11 + q] = fmaxf(acc[q], 0.f);
}

// ------ dense1: grid (gi=11, ob=2, fq=44); prefetched weight octets ---------
__global__ __launch_bounds__(128) void dense1_k(const float* __restrict__ Wc1) {
  __shared__ float zs[BATCH][FCH];
  int gi = blockIdx.x;
  int obase = blockIdx.y * 128;
  int fq = blockIdx.z, f0 = fq * FCH;
  int t = threadIdx.x;
  for (int i = t; i < BATCH * FCH; i += 128) {
    int gl = i >> 6, f = i & 63;
    zs[gl][f] = g_z[(size_t)(gl * NGPI + gi) * 2816 + f0 + f];
  }
  __syncthreads();
  const float* wp = Wc1 + (size_t)gi * 2816 * 256 + (size_t)f0 * 256 + obase + t;
  float acc[BATCH];
#pragma unroll
  for (int gl = 0; gl < BATCH; gl++) acc[gl] = 0.f;
  float wc[8];
#pragma unroll
  for (int r = 0; r < 8; r++) wc[r] = wp[(size_t)r * 256];
  for (int f = 0; f < FCH; f += 8) {
    float wn[8];
    int fn = (f + 8 < FCH) ? f + 8 : f;
#pragma unroll
    for (int r = 0; r < 8; r++) wn[r] = wp[(size_t)(fn + r) * 256];
#pragma unroll
    for (int gl = 0; gl < BATCH; gl++) {
      float4 z0 = *(const float4*)&zs[gl][f];
      float4 z1 = *(const float4*)&zs[gl][f + 4];
      acc[gl] += z0.x * wc[0] + z0.y * wc[1] + z0.z * wc[2] + z0.w * wc[3] +
                 z1.x * wc[4] + z1.y * wc[5] + z1.z * wc[6] + z1.w * wc[7];
    }
#pragma unroll
    for (int r = 0; r < 8; r++) wc[r] = wn[r];
  }
  float* hp = g_hp + (size_t)(gi * FQ + fq) * (BATCH * 256);
#pragma unroll
  for (int gl = 0; gl < BATCH; gl++)
    hp[gl * 256 + obase + t] = acc[gl];
}

// ---------------- reduce partials: h = sum over 484 slices ------------------
__global__ __launch_bounds__(256) void reduce_k() {
  int j = blockIdx.x * 256 + threadIdx.x;  // 48*256
  if (j >= BATCH * 256) return;
  float s0 = 0.f, s1 = 0.f, s2 = 0.f, s3 = 0.f;
  const size_t STR = BATCH * 256;
  for (int p = 0; p < NGPI * FQ; p += 4) {
    s0 += g_hp[(size_t)(p + 0) * STR + j];
    s1 += g_hp[(size_t)(p + 1) * STR + j];
    s2 += g_hp[(size_t)(p + 2) * STR + j];
    s3 += g_hp[(size_t)(p + 3) * STR + j];
  }
  g_h[j] = (s0 + s1) + (s2 + s3);
}

// ---------------- final dense (fp32 out) ------------------------------------
__global__ __launch_bounds__(256) void dense2_k(const float* __restrict__ bc1,
    const float* __restrict__ Wc2, const float* __restrict__ bc2,
    float* __restrict__ out) {
  __shared__ float hs[BATCH * 256];
  int t = threadIdx.x;
  for (int i = t; i < BATCH * 256; i += 256) {
    int o = i & 255;
    hs[i] = fmaxf(g_h[i] + bc1[o], 0.f);
  }
  __syncthreads();
  for (int i = t; i < 480; i += 256) {
    int b = i / 10, c = i % 10;
    float acc = bc2[c];
    for (int k = 0; k < 256; k++) acc += hs[b * 256 + k] * Wc2[k * 10 + c];
    out[i] = acc;
  }
}

// ---------------- diag: stamp out with launch-error code --------------------
__global__ void diag_k(float* __restrict__ out, float v) {
  int i = blockIdx.x * 256 + threadIdx.x;
  if (i < 480) out[i] = v;
}

// ---------------- launch ----------------------------------------------------
extern "C" void kernel_launch(void* const* d_in, const int* in_sizes, int n_in,
                              void* d_out, int out_size, void* d_ws, size_t ws_size,
                              hipStream_t stream) {
  const float* x   = (const float*)d_in[0];
  const int*   src = (const int*)d_in[1];
  const int*   dst = (const int*)d_in[2];
  const float* W1  = (const float*)d_in[3];
  const float* b1  = (const float*)d_in[4];
  const float* W2  = (const float*)d_in[5];
  const float* b2  = (const float*)d_in[6];
  const float* W3  = (const float*)d_in[7];
  const float* b3  = (const float*)d_in[8];
  const float* W4  = (const float*)d_in[9];
  const float* b4  = (const float*)d_in[10];
  const float* w5  = (const float*)d_in[11];
  const float* bc5 = (const float*)d_in[12];
  const float* w6  = (const float*)d_in[13];
  const float* bc6 = (const float*)d_in[14];
  const float* Wc1 = (const float*)d_in[15];
  const float* bc1 = (const float*)d_in[16];
  const float* Wc2 = (const float*)d_in[17];
  const float* bc2 = (const float*)d_in[18];
  float* out = (float*)d_out;

  (void)hipGetLastError();
  int lcount = 0, fidx = -1;
  hipError_t ferr = hipSuccess;
  auto ck = [&]() {
    hipError_t e = hipGetLastError();
    if (e != hipSuccess && ferr == hipSuccess) { ferr = e; fidx = lcount; }
    lcount++;
  };

  tw5_k<<<(128 * DCH + 255) / 256, 256, 0, stream>>>(w5); ck();
  tw6_k<<<(256 * 640 + 255) / 256, 256, 0, stream>>>(w6); ck();

  build_csr_k<<<GC, 192, 0, stream>>>(src, dst, 0); ck();
  gcn_k<true><<<GC * 4, 192, 0, stream>>>(x, 0, 0, W1, b1, 64); ck();
  gcn_k<false><<<GC * 4, 192, 0, stream>>>(nullptr, 0, 1, W2, b2, EMB); ck();
  gcn_k<false><<<GC * 4, 192, 0, stream>>>(nullptr, 1, 2, W3, b3, EMB); ck();
  gemm4_k<<<MC / 4, 256, 0, stream>>>(W4); ck();
  tail1_k<<<GC, 256, 0, stream>>>(b4); ck();
  conv5_k<<<dim3(GC, 6), 128, 0, stream>>>(bc5); ck();
  conv6_k<<<GC, 256, 0, stream>>>(bc6, 0); ck();

  dense1_k<<<dim3(NGPI, 2, FQ), 128, 0, stream>>>(Wc1); ck();
  reduce_k<<<(BATCH * 256 + 255) / 256, 256, 0, stream>>>(); ck();
  dense2_k<<<1, 256, 0, stream>>>(bc1, Wc2, bc2, out); ck();

  if (ferr != hipSuccess) {
    int code = (int)ferr; if (code > 100) code = 100;
    float v = (fidx == 0) ? (1024.f + 8.f * code) : (2048.f + 16.f * code);
    diag_k<<<2, 256, 0, stream>>>(out, v);
  }
}

// Round 11
// 927.355 us; speedup vs baseline: 1.3194x; 1.3194x over previous
//
#include <hip/hip_runtime.h>
#include <hip/hip_bf16.h>

#define EMB   256
#define KSORT 30
#define BATCH 48
#define NGPI  11
#define GG    528
#define NPG   192
#define EPG   384
#define DCH   769
#define GC    528                // graphs (single chunk)
#define MC    (GC*NPG)           // 101376 nodes
#define EC    (GC*EPG)           // 202752 edges
#define FQ    44                 // dense1 feature splits
#define FCH   (2816/FQ)          // 64 features per split
#define KB5   5                  // conv5 k-rows per block

__device__ __forceinline__ int clampi(int v, int lo, int hi) {
  return v < lo ? lo : (v > hi ? hi : v);
}

// ------------- static device scratch (~370 MB BSS; NEVER as host-side args) -
__device__ __attribute__((aligned(16))) float g_c1[MC * EMB];
__device__ __attribute__((aligned(16))) float g_c2[MC * EMB];
__device__ __attribute__((aligned(16))) float g_c3[MC * EMB];
__device__ __attribute__((aligned(16))) float g_tb[MC * EMB];
__device__ __attribute__((aligned(16))) float g_dis[MC];
__device__ __attribute__((aligned(16))) float g_s4[MC];      // layer-4 GEMV out
__device__ __attribute__((aligned(16))) float g_x4[MC];
__device__ __attribute__((aligned(16))) int   g_indptr[MC + 1];
__device__ __attribute__((aligned(16))) int   g_ssrc[EC];
__device__ __attribute__((aligned(16))) int   g_idx[GC * KSORT];
__device__ __attribute__((aligned(16))) float g_w5t[DCH * 128];
__device__ __attribute__((aligned(16))) float g_w6t[640 * 256];
__device__ __attribute__((aligned(16))) float g_y[GC * 128 * 30];
__device__ __attribute__((aligned(16))) float g_z[GG * 2816];
__device__ __attribute__((aligned(16))) float g_hp[NGPI * FQ * BATCH * 256];
__device__ __attribute__((aligned(16))) float g_h[BATCH * 256];

__device__ __forceinline__ float* selbuf(int s) {
  return s == 0 ? g_c1 : (s == 1 ? g_c2 : g_c3);
}

// -------- graph-local CSR build + degree norm (all 528 graphs) --------------
__global__ __launch_bounds__(192) void build_csr_k(const int* __restrict__ src,
    const int* __restrict__ dst, int g0) {
  __shared__ int cnt[NPG];
  __shared__ int offs[NPG];
  int g = blockIdx.x, t = threadIdx.x;
  int gg = g0 + g;
  cnt[t] = 0;
  __syncthreads();
  int ebase = gg * EPG, gnb = gg * NPG, lnb = g * NPG;
  for (int e = t; e < EPG; e += 192) {
    int dl = clampi(dst[ebase + e] - gnb, 0, NPG - 1);
    atomicAdd(&cnt[dl], 1);
  }
  __syncthreads();
  if (t == 0) {
    int run = g * EPG;
    for (int i = 0; i < NPG; i++) { offs[i] = run; run += cnt[i]; }
  }
  __syncthreads();
  g_indptr[lnb + t] = offs[t];
  g_dis[lnb + t] = 1.0f / sqrtf(1.0f + (float)cnt[t]);
  if (g == 0 && t == 0) g_indptr[MC] = EC;
  __syncthreads();
  for (int e = t; e < EPG; e += 192) {
    int ee = ebase + e;
    int dl = clampi(dst[ee] - gnb, 0, NPG - 1);
    int pos = clampi(atomicAdd(&offs[dl], 1), 0, EC - 1);
    g_ssrc[pos] = clampi(src[ee] - gnb, 0, NPG - 1) + lnb;
  }
}

// ---- fp32 tiled GEMM: g_tb[MC,256] = A[MC,Kd] @ W[Kd,256] ------------------
// R6 structure (128x128 tile, 8x8 micro-tile, dual-source B: LDS quad + L1
// quad, padded-broadcast A layout) with BK widened 16->32: one barrier pair
// covers 32 k-slices instead of 16, halving the barrier-drain stalls (the
// ~20% structural cost identified at R6). DS:FMA ratio unchanged. LDS
// 33.3KB -> 4 blocks/CU; prefetch regs +12 -> VGPR ~118 (<128 cliff).
// k-ascending accumulation per output element -> bit-stable output.
template<bool AX>
__global__ __launch_bounds__(256) void gemm_k(const float* __restrict__ Ax,
    int asel, const float* __restrict__ W, int Kd) {
  __shared__ float As[32 * 192];          // [kk][blk][12], 24.6 KB
  __shared__ float Bs[32][68];            // 32 k x 64 cols, 8.7 KB
  const int m0 = blockIdx.x * 128, n0 = blockIdx.y * 128;
  const int t = threadIdx.x;
  const int tx = t & 15, ty = t >> 4;
  const int arow = t >> 1, acol = (t & 1) * 8;
  const int awr = (arow >> 3) * 12 + (arow & 7);
  const int brow = t >> 4, bcol = tx * 4;    // stages rows brow and brow+16
  float acc[8][8];
#pragma unroll
  for (int i = 0; i < 8; i++)
#pragma unroll
    for (int j = 0; j < 8; j++) acc[i][j] = 0.f;
  const float* Ap = AX ? Ax : selbuf(asel);
  const float* arp = Ap + (size_t)(m0 + arow) * Kd + acol;
  const float* bsp  = W + (size_t)brow * EMB + n0 + bcol;
  const float* bsp2 = W + (size_t)(brow + 16) * EMB + n0 + bcol;
  const float* Wg = W + n0 + 64 + tx * 4;
  const int nt = Kd >> 5;                    // 32-k tiles (Kd=64 -> 2)
  float4 pa0 = *(const float4*)(arp);
  float4 pa1 = *(const float4*)(arp + 4);
  float4 pa2 = *(const float4*)(arp + 16);
  float4 pa3 = *(const float4*)(arp + 20);
  float4 pb0 = *(const float4*)(bsp);
  float4 pb1 = *(const float4*)(bsp2);
  for (int it = 0; it < nt; ++it) {
    As[(acol + 0) * 192 + awr] = pa0.x;
    As[(acol + 1) * 192 + awr] = pa0.y;
    As[(acol + 2) * 192 + awr] = pa0.z;
    As[(acol + 3) * 192 + awr] = pa0.w;
    As[(acol + 4) * 192 + awr] = pa1.x;
    As[(acol + 5) * 192 + awr] = pa1.y;
    As[(acol + 6) * 192 + awr] = pa1.z;
    As[(acol + 7) * 192 + awr] = pa1.w;
    As[(16 + acol + 0) * 192 + awr] = pa2.x;
    As[(16 + acol + 1) * 192 + awr] = pa2.y;
    As[(16 + acol + 2) * 192 + awr] = pa2.z;
    As[(16 + acol + 3) * 192 + awr] = pa2.w;
    As[(16 + acol + 4) * 192 + awr] = pa3.x;
    As[(16 + acol + 5) * 192 + awr] = pa3.y;
    As[(16 + acol + 6) * 192 + awr] = pa3.z;
    As[(16 + acol + 7) * 192 + awr] = pa3.w;
    *(float4*)&Bs[brow][bcol] = pb0;
    *(float4*)&Bs[brow + 16][bcol] = pb1;
    __syncthreads();
    if (it + 1 < nt) {                  // prefetch next 32-k tile into regs
      const float* ap = arp + (it + 1) * 32;
      pa0 = *(const float4*)(ap);
      pa1 = *(const float4*)(ap + 4);
      pa2 = *(const float4*)(ap + 16);
      pa3 = *(const float4*)(ap + 20);
      const size_t boff = (size_t)(it + 1) * 32 * EMB;
      pb0 = *(const float4*)(bsp + boff);
      pb1 = *(const float4*)(bsp2 + boff);
    }
    const float* Wk = Wg + (size_t)(it * 32) * EMB;
#pragma unroll
    for (int kk = 0; kk < 32; kk++) {
      float a[8], b[8];
      *(float4*)&a[0] = *(const float4*)&As[kk * 192 + ty * 12];
      *(float4*)&a[4] = *(const float4*)&As[kk * 192 + ty * 12 + 4];
      *(float4*)&b[0] = *(const float4*)&Bs[kk][bcol];
      *(float4*)&b[4] = *(const float4*)(Wk + kk * EMB);
#pragma unroll
      for (int i = 0; i < 8; i++)
#pragma unroll
        for (int j = 0; j < 8; j++) acc[i][j] += a[i] * b[j];
    }
    __syncthreads();
  }
#pragma unroll
  for (int i = 0; i < 8; i++) {
    float* cp = g_tb + (size_t)(m0 + ty * 8 + i) * EMB + n0 + tx * 4;
    *(float4*)cp = make_float4(acc[i][0], acc[i][1], acc[i][2], acc[i][3]);
    *(float4*)(cp + 64) = make_float4(acc[i][4], acc[i][5], acc[i][6], acc[i][7]);
  }
}

// ------- fused aggregation + self loop + bias + tanh ------------------------
// XCD-chunked block swizzle (bijective: 25344 = 8*3168): blocks of one graph
// stay on one XCD so the neighbor-gather window (196KB/graph) is L2-resident
// per XCD instead of being re-fetched by all 8 (R8/R9 evidence: ~110us saved
// across the 3 agg dispatches).
// When W4 != nullptr also computes the layer-4 GEMV (bit-identical to the
// old gemm4_k: same per-lane float4 dot + same __shfl_down order).
__global__ __launch_bounds__(256) void agg_k(int osel,
    const float* __restrict__ bias, const float* __restrict__ W4) {
  int nb = (blockIdx.x & 7) * (MC / 4 / 8) + (blockIdx.x >> 3);
  int n = nb * 4 + (threadIdx.x >> 6);
  int lane = threadIdx.x & 63;
  float dn = g_dis[n];
  const float4* H4 = (const float4*)g_tb;
  float4 hv = H4[(size_t)n * 64 + lane];
  float sc = dn * dn;
  float ax = hv.x * sc, ay = hv.y * sc, az = hv.z * sc, aw = hv.w * sc;
  int beg = g_indptr[n], end = g_indptr[n + 1];
  for (int j = beg; j < end; j++) {
    int s = g_ssrc[j];
    float c = g_dis[s] * dn;
    float4 v = H4[(size_t)s * 64 + lane];
    ax += v.x * c; ay += v.y * c; az += v.z * c; aw += v.w * c;
  }
  float4 bv = ((const float4*)bias)[lane];
  float4 o;
  o.x = tanhf(ax + bv.x);
  o.y = tanhf(ay + bv.y);
  o.z = tanhf(az + bv.z);
  o.w = tanhf(aw + bv.w);
  ((float4*)selbuf(osel))[(size_t)n * 64 + lane] = o;
  if (W4) {
    float4 w = ((const float4*)W4)[lane];
    float s = o.x * w.x + o.y * w.y + o.z * w.z + o.w * w.w;
    for (int off = 32; off > 0; off >>= 1) s += __shfl_down(s, off, 64);
    if (lane == 0) g_s4[n] = s;
  }
}

// ---- tail1: per-graph agg4 + bitonic sortpool (exact ports, merged) --------
__global__ __launch_bounds__(256) void tail1_k(const float* __restrict__ b4) {
  __shared__ float x4v[NPG];
  __shared__ float sv[256];
  __shared__ int si[256];
  const int g = blockIdx.x, t = threadIdx.x;
  const int gbase = g * NPG;
  if (t < NPG) {
    int n = gbase + t;
    float dn = g_dis[n];
    float acc = g_s4[n] * dn * dn;
    int beg = g_indptr[n], end = g_indptr[n + 1];
    for (int j = beg; j < end; j++) {
      int s = g_ssrc[j];
      acc += g_s4[s] * g_dis[s] * dn;
    }
    float v = tanhf(acc + b4[0]);
    x4v[t] = v;
    g_x4[n] = v;                       // conv5 reads this
  }
  __syncthreads();
  if (t < NPG) { sv[t] = x4v[t]; si[t] = t; }
  else { sv[t] = -1e30f; si[t] = 1 << 20; }
  __syncthreads();
  for (int k = 2; k <= 256; k <<= 1) {
    for (int j = k >> 1; j > 0; j >>= 1) {
      int ixj = t ^ j;
      if (ixj > t) {
        float v1 = sv[t], v2 = sv[ixj];
        int i1 = si[t], i2 = si[ixj];
        bool before_t = (v1 > v2) || (v1 == v2 && i1 < i2);
        bool up = ((t & k) == 0);
        if (up ? !before_t : before_t) {
          sv[t] = v2; sv[ixj] = v1;
          si[t] = i2; si[ixj] = i1;
        }
      }
      __syncthreads();
    }
  }
  if (t < KSORT) g_idx[g * KSORT + t] = clampi(gbase + si[t], 0, MC - 1);
}

// ---------------- weight transposes -----------------------------------------
__global__ __launch_bounds__(256) void tw5_k(const float* __restrict__ w5) {
  int i = blockIdx.x * 256 + threadIdx.x;  // 128*769
  if (i >= 128 * DCH) return;
  int o = i / DCH, d = i % DCH;
  g_w5t[d * 128 + o] = w5[i];
}
__global__ __launch_bounds__(256) void tw6_k(const float* __restrict__ w6) {
  int i = blockIdx.x * 256 + threadIdx.x;  // 256*640
  if (i >= 256 * 640) return;
  int o = i / 640, ir = i % 640;
  g_w6t[ir * 256 + o] = w6[i];
}

// ------ conv5: gather-GEMM over top-K rows; 5 rows/block, grid (GC,6) -------
__global__ __launch_bounds__(128) void conv5_k(const float* __restrict__ bc5) {
  __shared__ float ar[KB5][772];
  int g = blockIdx.x, kb = blockIdx.y * KB5;
  int t = threadIdx.x;
  for (int kk = 0; kk < KB5; kk++) {
    int n = clampi(g_idx[g * KSORT + kb + kk], 0, MC - 1);
    const float* p1 = g_c1 + (size_t)n * EMB;
    const float* p2 = g_c2 + (size_t)n * EMB;
    const float* p3 = g_c3 + (size_t)n * EMB;
    for (int d = t; d < EMB; d += 128) {
      ar[kk][d] = p1[d];
      ar[kk][EMB + d] = p2[d];
      ar[kk][2 * EMB + d] = p3[d];
    }
    if (t == 0) ar[kk][768] = g_x4[n];
  }
  __syncthreads();
  float acc[KB5];
  float bias = bc5[t];
#pragma unroll
  for (int kk = 0; kk < KB5; kk++) acc[kk] = bias;
  const float* wbase = g_w5t + t;
  int d = 0;
  for (; d + 8 <= DCH; d += 8) {
    float w0 = wbase[(d + 0) * 128], w1 = wbase[(d + 1) * 128];
    float w2 = wbase[(d + 2) * 128], w3 = wbase[(d + 3) * 128];
    float w4 = wbase[(d + 4) * 128], w5 = wbase[(d + 5) * 128];
    float w6 = wbase[(d + 6) * 128], w7 = wbase[(d + 7) * 128];
#pragma unroll
    for (int kk = 0; kk < KB5; kk++) {
      float4 a0 = *(const float4*)&ar[kk][d];
      float4 a1 = *(const float4*)&ar[kk][d + 4];
      acc[kk] += a0.x * w0 + a0.y * w1 + a0.z * w2 + a0.w * w3 +
                 a1.x * w4 + a1.y * w5 + a1.z * w6 + a1.w * w7;
    }
  }
  for (; d < DCH; d++) {
    float wv = wbase[d * 128];
#pragma unroll
    for (int kk = 0; kk < KB5; kk++) acc[kk] += ar[kk][d] * wv;
  }
#pragma unroll
  for (int kk = 0; kk < KB5; kk++)
    g_y[(size_t)g * 3840 + t * KSORT + kb + kk] = fmaxf(acc[kk], 0.f);
}

// ------ conv6 (128ch, k=5) per graph; maxpool(2,2) fused into staging -------
__global__ __launch_bounds__(256) void conv6_k(const float* __restrict__ bc6,
                                               int g0) {
  __shared__ float s[128 * 16];
  int g = blockIdx.x, t = threadIdx.x;
  for (int i = t; i < 1920; i += 256) {
    int ch = i / 15, j = i % 15;
    const float* yp = g_y + (size_t)g * 3840 + ch * 30 + 2 * j;
    s[ch * 16 + j] = fmaxf(yp[0], yp[1]);
  }
  __syncthreads();
  float acc[11];
  float bias = bc6[t];
#pragma unroll
  for (int q = 0; q < 11; q++) acc[q] = bias;
  for (int i = 0; i < 128; i += 2) {
    float wA[5], wB[5];
#pragma unroll
    for (int r = 0; r < 5; r++) {
      wA[r] = g_w6t[(i * 5 + r) * 256 + t];
      wB[r] = g_w6t[((i + 1) * 5 + r) * 256 + t];
    }
    const float* sA = &s[i * 16];
    const float* sB = &s[(i + 1) * 16];
#pragma unroll
    for (int r = 0; r < 5; r++)
#pragma unroll
      for (int q = 0; q < 11; q++)
        acc[q] += sA[r + q] * wA[r] + sB[r + q] * wB[r];
  }
#pragma unroll
  for (int q = 0; q < 11; q++)
    g_z[(size_t)(g0 + g) * 2816 + t * 11 + q] = fmaxf(acc[q], 0.f);
}

// ------ dense1: grid (gi=11, ob=2, fq=44); prefetched weight octets ---------
__global__ __launch_bounds__(128) void dense1_k(const float* __restrict__ Wc1) {
  __shared__ float zs[BATCH][FCH];
  int gi = blockIdx.x;
  int obase = blockIdx.y * 128;
  int fq = blockIdx.z, f0 = fq * FCH;
  int t = threadIdx.x;
  for (int i = t; i < BATCH * FCH; i += 128) {
    int gl = i >> 6, f = i & 63;
    zs[gl][f] = g_z[(size_t)(gl * NGPI + gi) * 2816 + f0 + f];
  }
  __syncthreads();
  const float* wp = Wc1 + (size_t)gi * 2816 * 256 + (size_t)f0 * 256 + obase + t;
  float acc[BATCH];
#pragma unroll
  for (int gl = 0; gl < BATCH; gl++) acc[gl] = 0.f;
  float wc[8];
#pragma unroll
  for (int r = 0; r < 8; r++) wc[r] = wp[(size_t)r * 256];
  for (int f = 0; f < FCH; f += 8) {
    float wn[8];
    int fn = (f + 8 < FCH) ? f + 8 : f;
#pragma unroll
    for (int r = 0; r < 8; r++) wn[r] = wp[(size_t)(fn + r) * 256];
#pragma unroll
    for (int gl = 0; gl < BATCH; gl++) {
      float4 z0 = *(const float4*)&zs[gl][f];
      float4 z1 = *(const float4*)&zs[gl][f + 4];
      acc[gl] += z0.x * wc[0] + z0.y * wc[1] + z0.z * wc[2] + z0.w * wc[3] +
                 z1.x * wc[4] + z1.y * wc[5] + z1.z * wc[6] + z1.w * wc[7];
    }
#pragma unroll
    for (int r = 0; r < 8; r++) wc[r] = wn[r];
  }
  float* hp = g_hp + (size_t)(gi * FQ + fq) * (BATCH * 256);
#pragma unroll
  for (int gl = 0; gl < BATCH; gl++)
    hp[gl * 256 + obase + t] = acc[gl];
}

// ---------------- reduce partials: h = sum over 484 slices ------------------
__global__ __launch_bounds__(256) void reduce_k() {
  int j = blockIdx.x * 256 + threadIdx.x;  // 48*256
  if (j >= BATCH * 256) return;
  float s0 = 0.f, s1 = 0.f, s2 = 0.f, s3 = 0.f;
  const size_t STR = BATCH * 256;
  for (int p = 0; p < NGPI * FQ; p += 4) {
    s0 += g_hp[(size_t)(p + 0) * STR + j];
    s1 += g_hp[(size_t)(p + 1) * STR + j];
    s2 += g_hp[(size_t)(p + 2) * STR + j];
    s3 += g_hp[(size_t)(p + 3) * STR + j];
  }
  g_h[j] = (s0 + s1) + (s2 + s3);
}

// ---------------- final dense (fp32 out) ------------------------------------
__global__ __launch_bounds__(256) void dense2_k(const float* __restrict__ bc1,
    const float* __restrict__ Wc2, const float* __restrict__ bc2,
    float* __restrict__ out) {
  __shared__ float hs[BATCH * 256];
  int t = threadIdx.x;
  for (int i = t; i < BATCH * 256; i += 256) {
    int o = i & 255;
    hs[i] = fmaxf(g_h[i] + bc1[o], 0.f);
  }
  __syncthreads();
  for (int i = t; i < 480; i += 256) {
    int b = i / 10, c = i % 10;
    float acc = bc2[c];
    for (int k = 0; k < 256; k++) acc += hs[b * 256 + k] * Wc2[k * 10 + c];
    out[i] = acc;
  }
}

// ---------------- diag: stamp out with launch-error code --------------------
__global__ void diag_k(float* __restrict__ out, float v) {
  int i = blockIdx.x * 256 + threadIdx.x;
  if (i < 480) out[i] = v;
}

// ---------------- launch ----------------------------------------------------
extern "C" void kernel_launch(void* const* d_in, const int* in_sizes, int n_in,
                              void* d_out, int out_size, void* d_ws, size_t ws_size,
                              hipStream_t stream) {
  const float* x   = (const float*)d_in[0];
  const int*   src = (const int*)d_in[1];
  const int*   dst = (const int*)d_in[2];
  const float* W1  = (const float*)d_in[3];
  const float* b1  = (const float*)d_in[4];
  const float* W2  = (const float*)d_in[5];
  const float* b2  = (const float*)d_in[6];
  const float* W3  = (const float*)d_in[7];
  const float* b3  = (const float*)d_in[8];
  const float* W4  = (const float*)d_in[9];
  const float* b4  = (const float*)d_in[10];
  const float* w5  = (const float*)d_in[11];
  const float* bc5 = (const float*)d_in[12];
  const float* w6  = (const float*)d_in[13];
  const float* bc6 = (const float*)d_in[14];
  const float* Wc1 = (const float*)d_in[15];
  const float* bc1 = (const float*)d_in[16];
  const float* Wc2 = (const float*)d_in[17];
  const float* bc2 = (const float*)d_in[18];
  float* out = (float*)d_out;

  (void)hipGetLastError();
  int lcount = 0, fidx = -1;
  hipError_t ferr = hipSuccess;
  auto ck = [&]() {
    hipError_t e = hipGetLastError();
    if (e != hipSuccess && ferr == hipSuccess) { ferr = e; fidx = lcount; }
    lcount++;
  };

  tw5_k<<<(128 * DCH + 255) / 256, 256, 0, stream>>>(w5); ck();
  tw6_k<<<(256 * 640 + 255) / 256, 256, 0, stream>>>(w6); ck();

  dim3 gg(MC / 128, 2);
  build_csr_k<<<GC, 192, 0, stream>>>(src, dst, 0); ck();
  gemm_k<true><<<gg, 256, 0, stream>>>(x, 0, W1, 64); ck();
  agg_k<<<MC / 4, 256, 0, stream>>>(0, b1, nullptr); ck();
  gemm_k<false><<<gg, 256, 0, stream>>>(nullptr, 0, W2, EMB); ck();
  agg_k<<<MC / 4, 256, 0, stream>>>(1, b2, nullptr); ck();
  gemm_k<false><<<gg, 256, 0, stream>>>(nullptr, 1, W3, EMB); ck();
  agg_k<<<MC / 4, 256, 0, stream>>>(2, b3, W4); ck();
  tail1_k<<<GC, 256, 0, stream>>>(b4); ck();
  conv5_k<<<dim3(GC, 6), 128, 0, stream>>>(bc5); ck();
  conv6_k<<<GC, 256, 0, stream>>>(bc6, 0); ck();

  dense1_k<<<dim3(NGPI, 2, FQ), 128, 0, stream>>>(Wc1); ck();
  reduce_k<<<(BATCH * 256 + 255) / 256, 256, 0, stream>>>(); ck();
  dense2_k<<<1, 256, 0, stream>>>(bc1, Wc2, bc2, out); ck();

  if (ferr != hipSuccess) {
    int code = (int)ferr; if (code > 100) code = 100;
    float v = (fidx == 0) ? (1024.f + 8.f * code) : (2048.f + 16.f * code);
    diag_k<<<2, 256, 0, stream>>>(out, v);
  }
}